// Round 4
// baseline (169.984 us; speedup 1.0000x reference)
//
#include <hip/hip_runtime.h>

typedef unsigned short u16;
typedef __bf16 bf16x8 __attribute__((ext_vector_type(8)));
typedef float f32x4 __attribute__((ext_vector_type(4)));

#define DEV static __device__ __forceinline__

DEV float bf2f(u16 u) { unsigned x = ((unsigned)u) << 16; return __builtin_bit_cast(float, x); }
DEV u16 f2bf(float f) {
  unsigned u = __builtin_bit_cast(unsigned, f);
  u += 0x7FFFu + ((u >> 16) & 1u);
  return (u16)(u >> 16);
}
DEV int swz(int b) { return b ^ ((((b >> 7) & 7)) << 4); }  // for 128B-stride LDS

#define GLD_LDS16(gp, lp)                                                    \
  __builtin_amdgcn_global_load_lds(                                          \
      (__attribute__((address_space(1))) void*)(void*)(gp),                  \
      (__attribute__((address_space(3))) void*)(lp), 16, 0, 0)

#define BAR() __builtin_amdgcn_s_barrier()
#define WAIT_LGKM0()                                                         \
  { asm volatile("s_waitcnt lgkmcnt(0)" ::: "memory");                       \
    __builtin_amdgcn_sched_barrier(0); }
#define WAIT_VM(n) asm volatile("s_waitcnt vmcnt(" #n ")" ::: "memory")

// ---------------------------------------------------------------------------
// fp32 -> bf16 bulk convert (8 elems/thread)
// ---------------------------------------------------------------------------
__global__ __launch_bounds__(256) void convert_bf16_kernel(
    const float* __restrict__ in, u16* __restrict__ out) {
  const size_t i = (size_t)blockIdx.x * 256 + threadIdx.x;
  const float4* p = (const float4*)in + 2 * i;
  float4 a = p[0], b = p[1];
  unsigned w0 = (unsigned)f2bf(a.x) | ((unsigned)f2bf(a.y) << 16);
  unsigned w1 = (unsigned)f2bf(a.z) | ((unsigned)f2bf(a.w) << 16);
  unsigned w2 = (unsigned)f2bf(b.x) | ((unsigned)f2bf(b.y) << 16);
  unsigned w3 = (unsigned)f2bf(b.z) | ((unsigned)f2bf(b.w) << 16);
  ((uint4*)out)[i] = make_uint4(w0, w1, w2, w3);
}

// ---------------------------------------------------------------------------
// Transpose + fp32->bf16 convert:  W[K][Ncols] -> Wt[Ncols][K]
// ---------------------------------------------------------------------------
__global__ void transpose_bf16(const float* __restrict__ W, u16* __restrict__ Wt,
                               int K, int Ncols) {
  __shared__ float t[32][33];
  const int tx = threadIdx.x & 31, ty = threadIdx.x >> 5;  // 32 x 8
  const int n0 = blockIdx.x * 32, k0 = blockIdx.y * 32;
#pragma unroll
  for (int i = 0; i < 4; ++i)
    t[ty + i * 8][tx] = W[(size_t)(k0 + ty + i * 8) * Ncols + n0 + tx];
  __syncthreads();
#pragma unroll
  for (int i = 0; i < 4; ++i)
    Wt[(size_t)(n0 + ty + i * 8) * K + k0 + tx] = f2bf(t[tx][ty + i * 8]);
}

// ---------------------------------------------------------------------------
// 256x256 8-phase GEMM (T2+T3+T4+T5), BK=64, K=512 (8 K-tiles), 512 thr.
// MODE 0: NX=6; epilogue elu+1 -> q/k/v in NATIVE frag layout
//         [rb16][cb16][lane64][r4] (coalesced dwordx2 stores).
// MODE 1: NX=2; epilogue + bias -> fp32 row-major (64B-sector stores).
// ---------------------------------------------------------------------------
template <int MODE>
__global__ __launch_bounds__(512, 2) void gemm8_kernel(
    const u16* __restrict__ A, const u16* __restrict__ Bt,
    u16* __restrict__ qb, u16* __restrict__ kb, u16* __restrict__ vb,
    float* __restrict__ Cf, const float* __restrict__ bias) {
  constexpr int NX = (MODE == 0) ? 6 : 2;
  constexpr int K = 512;
  __shared__ __align__(16) u16 As[2][2][8192];  // 64 KB
  __shared__ __align__(16) u16 Bs[2][2][8192];  // 64 KB

  const int tid = threadIdx.x;
  const int lane = tid & 63;
  const int wid = tid >> 6;   // 0..7
  const int wr = wid >> 2;    // 0..1  (M)
  const int wcn = wid & 3;    // 0..3  (N)

  const int nwg = gridDim.x;
  const int pb = blockIdx.x;
  const int logical = (pb & 7) * (nwg >> 3) + (pb >> 3);
  const int rowBase = (logical / NX) * 256;
  const int colBase = (logical % NX) * 256;

  int soff[2], od[2];
#pragma unroll
  for (int i = 0; i < 2; ++i) {
    int o = (wid * 2 + i) * 1024 + lane * 16;        // linear dest byte
    int a = o ^ (((o >> 7) & 7) << 4);               // swizzled source coord
    soff[i] = (a >> 7) * K + ((a & 127) >> 1);       // element offset in panel
    od[i] = (wid * 2 + i) * 512;                     // dest base (elements)
  }
  const u16* Abase = A + (size_t)rowBase * K;
  const u16* Bbase = Bt + (size_t)colBase * K;

#define STAGE_A(tau, h)                                                      \
  { const u16* g = Abase + (size_t)(h)*128 * K + (tau)*64;                   \
    _Pragma("unroll") for (int i = 0; i < 2; ++i)                            \
        GLD_LDS16(g + soff[i], &As[(tau)&1][h][od[i]]); }
#define STAGE_B(tau, h)                                                      \
  { const u16* g = Bbase + (size_t)(h)*128 * K + (tau)*64;                   \
    _Pragma("unroll") for (int i = 0; i < 2; ++i)                            \
        GLD_LDS16(g + soff[i], &Bs[(tau)&1][h][od[i]]); }

  const int sx = (lane & 7) << 4;
  int rb[2];
#pragma unroll
  for (int ks = 0; ks < 2; ++ks)
    rb[ks] = ((lane & 15) * 128 + ks * 64 + (lane >> 4) * 16) ^ sx;
  const char* Ahalf[2] = {(const char*)&As[0][wr][0], (const char*)&As[1][wr][0]};
  const char* Bhalf[2] = {(const char*)&Bs[0][wcn >> 1][0], (const char*)&Bs[1][wcn >> 1][0]};

  bf16x8 aA[4][2], bB0[2][2], bB1[2][2];
  f32x4 acc[8][4];
  f32x4 zv = {0.f, 0.f, 0.f, 0.f};
#pragma unroll
  for (int m = 0; m < 8; ++m)
#pragma unroll
    for (int n = 0; n < 4; ++n) acc[m][n] = zv;

#define LDA_FRAGS(par, mh)                                                   \
  _Pragma("unroll") for (int m = 0; m < 4; ++m)                              \
      _Pragma("unroll") for (int ks = 0; ks < 2; ++ks)                       \
          aA[m][ks] = *(const bf16x8*)(Ahalf[par] + (mh)*8192 + m * 2048 + rb[ks]);
#define LDB_FRAGS(par, nh, dst)                                              \
  _Pragma("unroll") for (int n = 0; n < 2; ++n)                              \
      _Pragma("unroll") for (int ks = 0; ks < 2; ++ks)                       \
          dst[n][ks] = *(const bf16x8*)(Bhalf[par] + (wcn & 1) * 8192 +      \
                                        (nh)*4096 + n * 2048 + rb[ks]);
#define MFMA_QUAD(mh, nh, bsrc)                                              \
  __builtin_amdgcn_s_setprio(1);                                             \
  _Pragma("unroll") for (int m = 0; m < 4; ++m)                              \
      _Pragma("unroll") for (int n = 0; n < 2; ++n)                          \
          _Pragma("unroll") for (int ks = 0; ks < 2; ++ks)                   \
              acc[(mh)*4 + m][(nh)*2 + n] =                                  \
                  __builtin_amdgcn_mfma_f32_16x16x32_bf16(                   \
                      aA[m][ks], bsrc[n][ks], acc[(mh)*4 + m][(nh)*2 + n],   \
                      0, 0, 0);                                              \
  __builtin_amdgcn_s_setprio(0);

  // ---- prologue
  STAGE_A(0, 0); STAGE_A(0, 1); STAGE_B(0, 0); STAGE_B(0, 1);
  STAGE_B(1, 0); STAGE_A(1, 0);
  WAIT_VM(4);
  BAR();

  for (int t = 0; t < 6; t += 2) {
    LDA_FRAGS(0, 0); LDB_FRAGS(0, 0, bB0);
    STAGE_B(t + 1, 1);
    BAR(); WAIT_LGKM0();
    MFMA_QUAD(0, 0, bB0);
    BAR();
    LDB_FRAGS(0, 1, bB1);
    STAGE_A(t + 1, 1);
    BAR(); WAIT_LGKM0();
    MFMA_QUAD(0, 1, bB1);
    BAR();
    LDA_FRAGS(0, 1);
    STAGE_B(t + 2, 0);
    BAR(); WAIT_LGKM0();
    MFMA_QUAD(1, 1, bB1);
    BAR();
    STAGE_A(t + 2, 0);
    BAR(); WAIT_LGKM0();
    MFMA_QUAD(1, 0, bB0);
    WAIT_VM(4);
    BAR();
    LDA_FRAGS(1, 0); LDB_FRAGS(1, 0, bB0);
    STAGE_A(t + 2, 1);
    BAR(); WAIT_LGKM0();
    MFMA_QUAD(0, 0, bB0);
    BAR();
    LDB_FRAGS(1, 1, bB1);
    STAGE_B(t + 2, 1);
    BAR(); WAIT_LGKM0();
    MFMA_QUAD(0, 1, bB1);
    BAR();
    LDA_FRAGS(1, 1);
    STAGE_B(t + 3, 0);
    BAR(); WAIT_LGKM0();
    MFMA_QUAD(1, 1, bB1);
    BAR();
    STAGE_A(t + 3, 0);
    BAR(); WAIT_LGKM0();
    MFMA_QUAD(1, 0, bB0);
    WAIT_VM(4);
    BAR();
  }

  // ---- drain pair (6,7)
  LDA_FRAGS(0, 0); LDB_FRAGS(0, 0, bB0);
  STAGE_B(7, 1);
  BAR(); WAIT_LGKM0();
  MFMA_QUAD(0, 0, bB0);
  BAR();
  LDB_FRAGS(0, 1, bB1);
  STAGE_A(7, 1);
  BAR(); WAIT_LGKM0();
  MFMA_QUAD(0, 1, bB1);
  BAR();
  LDA_FRAGS(0, 1);
  BAR(); WAIT_LGKM0();
  MFMA_QUAD(1, 1, bB1);
  BAR();
  BAR(); WAIT_LGKM0();
  MFMA_QUAD(1, 0, bB0);
  WAIT_VM(0);
  BAR();
  LDA_FRAGS(1, 0); LDB_FRAGS(1, 0, bB0);
  BAR(); WAIT_LGKM0();
  MFMA_QUAD(0, 0, bB0);
  BAR();
  LDB_FRAGS(1, 1, bB1);
  BAR(); WAIT_LGKM0();
  MFMA_QUAD(0, 1, bB1);
  BAR();
  LDA_FRAGS(1, 1);
  BAR(); WAIT_LGKM0();
  MFMA_QUAD(1, 1, bB1);
  BAR();
  BAR(); WAIT_LGKM0();
  MFMA_QUAD(1, 0, bB0);

  // ---- epilogue
  if (MODE == 0) {
    // NATIVE layout: [rb][cb][lane][r4]; coalesced 8B stores (512B/wave-inst)
    u16* dst = (colBase < 512) ? qb : (colBase < 1024) ? kb : vb;
    const int cb2 = colBase & 511;
    const bool doelu = (colBase < 1024);
    const int rbBase = (rowBase >> 4) + wr * 8;
    const int cbBase = (cb2 >> 4) + wcn * 4;
#pragma unroll
    for (int mi = 0; mi < 8; ++mi) {
#pragma unroll
      for (int ni = 0; ni < 4; ++ni) {
        float v[4];
#pragma unroll
        for (int r = 0; r < 4; ++r) {
          float t2 = acc[mi][ni][r];
          v[r] = doelu ? ((t2 > 0.f) ? t2 + 1.f : __expf(t2)) : t2;
        }
        unsigned lo = (unsigned)f2bf(v[0]) | ((unsigned)f2bf(v[1]) << 16);
        unsigned hi = (unsigned)f2bf(v[2]) | ((unsigned)f2bf(v[3]) << 16);
        size_t base = (((size_t)(rbBase + mi) * 32 + (cbBase + ni)) * 64 + lane) * 4;
        *(uint2*)(dst + base) = make_uint2(lo, hi);
      }
    }
  } else {
#pragma unroll
    for (int mi = 0; mi < 8; ++mi) {
#pragma unroll
      for (int ni = 0; ni < 4; ++ni) {
        const int col = colBase + wcn * 64 + ni * 16 + (lane & 15);
#pragma unroll
        for (int r = 0; r < 4; ++r) {
          const int row = rowBase + wr * 128 + mi * 16 + (lane >> 4) * 4 + r;
          Cf[(size_t)row * 512 + col] = acc[mi][ni][r] + bias[col];
        }
      }
    }
  }
#undef STAGE_A
#undef STAGE_B
#undef LDA_FRAGS
#undef LDB_FRAGS
#undef MFMA_QUAD
}

// ---------------------------------------------------------------------------
// kv partials, reading NATIVE k/v. acc[d][e] += k[n][d]*v[n][e]; ksum.
// part[bh][chunk][64][80] (col 64 = ksum).
// ---------------------------------------------------------------------------
__global__ __launch_bounds__(256, 2) void kv_partial_kernel(
    const u16* __restrict__ kb, const u16* __restrict__ vb,
    float* __restrict__ part) {
  __shared__ float kf[128][64];
  __shared__ float vf[128][64];
  const int tid = threadIdx.x;
  const int chunk = blockIdx.x;  // 0..15
  const int bh = blockIdx.y;     // 0..31
  const int b = bh >> 3, h = bh & 7;
  const size_t rbase = (size_t)b * 8192;
  const int hcb = h * 4;
  const int dg = tid >> 4, eg = tid & 15;

  float acc[4][4] = {};
  float ks[4] = {};

  for (int st = 0; st < 4; ++st) {
    const int n0 = chunk * 512 + st * 128;
    const int rbT = (int)((rbase + n0) >> 4);
#pragma unroll
    for (int it = 0; it < 4; ++it) {
      int flat = it * 256 + tid;           // 0..1023
      int frag = flat >> 5, w = flat & 31;
      int rb_i = frag >> 2, cb_i = frag & 3;
      size_t src = (((size_t)(rbT + rb_i) * 32 + hcb + cb_i) * 64 + w * 2) * 4;
      uint4 kraw = *(const uint4*)(kb + src);
      uint4 vraw = *(const uint4*)(vb + src);
      int l0 = w * 2;
      int row0 = rb_i * 16 + ((l0 >> 4) << 2);
      int col0 = cb_i * 16 + (l0 & 15);
      // kraw = [l0.r0,l0.r1 | l0.r2,l0.r3 | l1.r0,l1.r1 | l1.r2,l1.r3]
      *(float2*)&kf[row0 + 0][col0] = make_float2(bf2f((u16)(kraw.x & 0xFFFF)), bf2f((u16)(kraw.z & 0xFFFF)));
      *(float2*)&kf[row0 + 1][col0] = make_float2(bf2f((u16)(kraw.x >> 16)), bf2f((u16)(kraw.z >> 16)));
      *(float2*)&kf[row0 + 2][col0] = make_float2(bf2f((u16)(kraw.y & 0xFFFF)), bf2f((u16)(kraw.w & 0xFFFF)));
      *(float2*)&kf[row0 + 3][col0] = make_float2(bf2f((u16)(kraw.y >> 16)), bf2f((u16)(kraw.w >> 16)));
      *(float2*)&vf[row0 + 0][col0] = make_float2(bf2f((u16)(vraw.x & 0xFFFF)), bf2f((u16)(vraw.z & 0xFFFF)));
      *(float2*)&vf[row0 + 1][col0] = make_float2(bf2f((u16)(vraw.x >> 16)), bf2f((u16)(vraw.z >> 16)));
      *(float2*)&vf[row0 + 2][col0] = make_float2(bf2f((u16)(vraw.y & 0xFFFF)), bf2f((u16)(vraw.w & 0xFFFF)));
      *(float2*)&vf[row0 + 3][col0] = make_float2(bf2f((u16)(vraw.y >> 16)), bf2f((u16)(vraw.w >> 16)));
    }
    __syncthreads();
#pragma unroll 4
    for (int n = 0; n < 128; ++n) {
      float4 kk = *(const float4*)&kf[n][dg * 4];
      float4 vv = *(const float4*)&vf[n][eg * 4];
      float ka[4] = {kk.x, kk.y, kk.z, kk.w};
      float va[4] = {vv.x, vv.y, vv.z, vv.w};
#pragma unroll
      for (int i = 0; i < 4; ++i)
#pragma unroll
        for (int j = 0; j < 4; ++j) acc[i][j] += ka[i] * va[j];
      if (eg == 0) {
#pragma unroll
        for (int i = 0; i < 4; ++i) ks[i] += ka[i];
      }
    }
    __syncthreads();
  }

  float* pp = part + ((size_t)bh * 16 + chunk) * (64 * 80);
#pragma unroll
  for (int i = 0; i < 4; ++i) {
#pragma unroll
    for (int j = 0; j < 4; ++j) pp[(dg * 4 + i) * 80 + eg * 4 + j] = acc[i][j];
    if (eg == 0) pp[(dg * 4 + i) * 80 + 64] = ks[i];
  }
}

// ---------------------------------------------------------------------------
// Reduce partials over chunks -> kv_ext[bh][64][80]; cols 65..79 zeroed.
// ---------------------------------------------------------------------------
__global__ void kv_reduce_kernel(const float* __restrict__ part,
                                 float* __restrict__ kv_ext) {
  const int idx = blockIdx.x * 256 + threadIdx.x;
  const int bh = idx / 5120;
  const int de = idx % 5120;
  const int e = de % 80;
  float s = 0.f;
  if (e <= 64) {
    for (int c = 0; c < 16; ++c) s += part[((size_t)bh * 16 + c) * 5120 + de];
  }
  kv_ext[idx] = s;
}

// ---------------------------------------------------------------------------
// attn = (q @ kv) * z, q read NATIVE, output written ROW-MAJOR via per-wave
// LDS transpose (XOR-swizzled qs; also fixes the 16-way frag-read conflict).
// ---------------------------------------------------------------------------
__global__ __launch_bounds__(256, 2) void attn_kernel(
    const u16* __restrict__ qb, const float* __restrict__ kv_ext,
    u16* __restrict__ attn) {
  __shared__ __align__(16) float kvs[64 * 80];
  __shared__ __align__(16) u16 qs[4][64 * 64];
  const int tid = threadIdx.x, lane = tid & 63, wid = tid >> 6;
  const int nchunk = blockIdx.x, bh = blockIdx.y;
  const int b = bh >> 3, h = bh & 7;

#pragma unroll
  for (int i = 0; i < 20; ++i)
    kvs[i * 256 + tid] = kv_ext[(size_t)bh * 5120 + i * 256 + tid];
  __syncthreads();

  bf16x8 bfr[5][2];
#pragma unroll
  for (int eb = 0; eb < 5; ++eb)
#pragma unroll
    for (int ksi = 0; ksi < 2; ++ksi) {
      unsigned pw[4];
#pragma unroll
      for (int jj = 0; jj < 4; ++jj) {
        int d0 = ksi * 32 + (lane >> 4) * 8 + 2 * jj;
        int e = eb * 16 + (lane & 15);
        unsigned lo = f2bf(kvs[d0 * 80 + e]);
        unsigned hi = f2bf(kvs[(d0 + 1) * 80 + e]);
        pw[jj] = lo | (hi << 16);
      }
      uint4 u = make_uint4(pw[0], pw[1], pw[2], pw[3]);
      bfr[eb][ksi] = __builtin_bit_cast(bf16x8, u);
    }

  // stage this wave's 64 q rows from NATIVE layout into row-major swizzled qs
  const size_t row0 = (size_t)b * 8192 + (size_t)nchunk * 256 + wid * 64;
  const int rbQ = (int)(row0 >> 4);
  const int hcbQ = h * 4;
  char* qsw = (char*)&qs[wid][0];
#pragma unroll
  for (int it = 0; it < 8; ++it) {
    int flat = it * 64 + lane;            // 0..511
    int frag = flat >> 5, w = flat & 31;
    int rb_i = frag >> 2, cb_i = frag & 3;
    size_t src = (((size_t)(rbQ + rb_i) * 32 + hcbQ + cb_i) * 64 + w * 2) * 4;
    uint4 q4 = *(const uint4*)(qb + src);
    int l0 = w * 2;
    int row = rb_i * 16 + ((l0 >> 4) << 2);
    int col = cb_i * 16 + (l0 & 15);
    int bb = row * 128 + col * 2;
    *(unsigned*)(qsw + swz(bb)) = (q4.x & 0xFFFF) | ((q4.z & 0xFFFF) << 16);
    *(unsigned*)(qsw + swz(bb + 128)) = (q4.x >> 16) | (q4.z & 0xFFFF0000u);
    *(unsigned*)(qsw + swz(bb + 256)) = (q4.y & 0xFFFF) | ((q4.w & 0xFFFF) << 16);
    *(unsigned*)(qsw + swz(bb + 384)) = (q4.y >> 16) | (q4.w & 0xFFFF0000u);
  }
  WAIT_LGKM0();

  f32x4 zv = {0.f, 0.f, 0.f, 0.f};
  f32x4 acc[4][5];
#pragma unroll
  for (int m = 0; m < 4; ++m)
#pragma unroll
    for (int eb = 0; eb < 5; ++eb) acc[m][eb] = zv;

#pragma unroll
  for (int m = 0; m < 4; ++m)
#pragma unroll
    for (int ksi = 0; ksi < 2; ++ksi) {
      int bb = (m * 16 + (lane & 15)) * 128 + (ksi * 32 + (lane >> 4) * 8) * 2;
      bf16x8 af = *(const bf16x8*)(qsw + swz(bb));
#pragma unroll
      for (int eb = 0; eb < 5; ++eb)
        acc[m][eb] = __builtin_amdgcn_mfma_f32_16x16x32_bf16(af, bfr[eb][ksi], acc[m][eb], 0, 0, 0);
    }

  // scale + per-wave LDS transpose (qs[wid] is dead now) -> coalesced stores
#pragma unroll
  for (int m = 0; m < 4; ++m) {
#pragma unroll
    for (int r = 0; r < 4; ++r) {
      float den = __shfl(acc[m][4][r], lane & ~15, 64);
      float zr = 1.f / (den + 1e-6f);
      int row = m * 16 + (lane >> 4) * 4 + r;
#pragma unroll
      for (int eb = 0; eb < 4; ++eb) {
        int col = eb * 16 + (lane & 15);
        *(u16*)(qsw + swz(row * 128 + col * 2)) = f2bf(acc[m][eb][r] * zr);
      }
    }
  }
  WAIT_LGKM0();
#pragma unroll
  for (int jt = 0; jt < 8; ++jt) {
    int flat = jt * 64 + lane;            // 64 rows x 8 x 16B
    int row = flat >> 3, w = flat & 7;
    uint4 val = *(const uint4*)(qsw + swz(row * 128 + w * 16));
    *(uint4*)(attn + (row0 + row) * 512 + h * 64 + w * 8) = val;
  }
}

// ---------------------------------------------------------------------------
extern "C" void kernel_launch(void* const* d_in, const int* in_sizes, int n_in,
                              void* d_out, int out_size, void* d_ws, size_t ws_size,
                              hipStream_t stream) {
  const float* x = (const float*)d_in[0];
  const float* Wqkv = (const float*)d_in[1];
  const float* Wout = (const float*)d_in[2];
  const float* bout = (const float*)d_in[3];
  float* out = (float*)d_out;

  char* ws = (char*)d_ws;
  u16* qb = (u16*)ws;        ws += (size_t)32768 * 512 * 2;  // native
  u16* kb = (u16*)ws;        ws += (size_t)32768 * 512 * 2;  // native
  u16* vb = (u16*)ws;        ws += (size_t)32768 * 512 * 2;  // native; reused row-major as attn
  u16* wqkv_t = (u16*)ws;    ws += (size_t)1536 * 512 * 2;
  u16* wout_t = (u16*)ws;    ws += (size_t)512 * 512 * 2;
  float* kv_ext = (float*)ws; ws += (size_t)32 * 64 * 80 * 4;
  float* part = (float*)ws;   ws += (size_t)32 * 16 * 64 * 80 * 4;

  u16* xb = (u16*)d_out;  // dead until gemm1 overwrites d_out

  convert_bf16_kernel<<<8192, 256, 0, stream>>>(x, xb);
  transpose_bf16<<<dim3(1536 / 32, 512 / 32), 256, 0, stream>>>(Wqkv, wqkv_t, 512, 1536);
  transpose_bf16<<<dim3(512 / 32, 512 / 32), 256, 0, stream>>>(Wout, wout_t, 512, 512);
  gemm8_kernel<0><<<768, 512, 0, stream>>>(xb, wqkv_t, qb, kb, vb, nullptr, nullptr);
  kv_partial_kernel<<<dim3(16, 32), 256, 0, stream>>>(kb, vb, part);
  kv_reduce_kernel<<<640, 256, 0, stream>>>(part, kv_ext);
  attn_kernel<<<dim3(32, 32), 256, 0, stream>>>(qb, kv_ext, vb);
  gemm8_kernel<1><<<256, 512, 0, stream>>>(vb, wout_t, nullptr, nullptr, nullptr, out, bout);
}

// Round 5
// 144.491 us; speedup vs baseline: 1.1764x; 1.1764x over previous
//
#include <hip/hip_runtime.h>

typedef unsigned short u16;
typedef __bf16 bf16x8 __attribute__((ext_vector_type(8)));
typedef float f32x4 __attribute__((ext_vector_type(4)));

#define DEV static __device__ __forceinline__

DEV float bf2f(u16 u) { unsigned x = ((unsigned)u) << 16; return __builtin_bit_cast(float, x); }
DEV u16 f2bf(float f) {
  unsigned u = __builtin_bit_cast(unsigned, f);
  u += 0x7FFFu + ((u >> 16) & 1u);
  return (u16)(u >> 16);
}
DEV int swz(int b) { return b ^ ((((b >> 7) & 7)) << 4); }  // for 128B-stride LDS

#define GLD_LDS16(gp, lp)                                                    \
  __builtin_amdgcn_global_load_lds(                                          \
      (__attribute__((address_space(1))) void*)(void*)(gp),                  \
      (__attribute__((address_space(3))) void*)(lp), 16, 0, 0)

#define BAR() __builtin_amdgcn_s_barrier()
#define WAIT_LGKM0()                                                         \
  { asm volatile("s_waitcnt lgkmcnt(0)" ::: "memory");                       \
    __builtin_amdgcn_sched_barrier(0); }
#define WAIT_VM(n) asm volatile("s_waitcnt vmcnt(" #n ")" ::: "memory")

// ---------------------------------------------------------------------------
// fp32 -> bf16 bulk convert (8 elems/thread)
// ---------------------------------------------------------------------------
__global__ __launch_bounds__(256) void convert_bf16_kernel(
    const float* __restrict__ in, u16* __restrict__ out) {
  const size_t i = (size_t)blockIdx.x * 256 + threadIdx.x;
  const float4* p = (const float4*)in + 2 * i;
  float4 a = p[0], b = p[1];
  unsigned w0 = (unsigned)f2bf(a.x) | ((unsigned)f2bf(a.y) << 16);
  unsigned w1 = (unsigned)f2bf(a.z) | ((unsigned)f2bf(a.w) << 16);
  unsigned w2 = (unsigned)f2bf(b.x) | ((unsigned)f2bf(b.y) << 16);
  unsigned w3 = (unsigned)f2bf(b.z) | ((unsigned)f2bf(b.w) << 16);
  ((uint4*)out)[i] = make_uint4(w0, w1, w2, w3);
}

// ---------------------------------------------------------------------------
// Transpose + fp32->bf16 convert:  W[K][Ncols] -> Wt[Ncols][K]
// ---------------------------------------------------------------------------
__global__ void transpose_bf16(const float* __restrict__ W, u16* __restrict__ Wt,
                               int K, int Ncols) {
  __shared__ float t[32][33];
  const int tx = threadIdx.x & 31, ty = threadIdx.x >> 5;  // 32 x 8
  const int n0 = blockIdx.x * 32, k0 = blockIdx.y * 32;
#pragma unroll
  for (int i = 0; i < 4; ++i)
    t[ty + i * 8][tx] = W[(size_t)(k0 + ty + i * 8) * Ncols + n0 + tx];
  __syncthreads();
#pragma unroll
  for (int i = 0; i < 4; ++i)
    Wt[(size_t)(n0 + ty + i * 8) * K + k0 + tx] = f2bf(t[tx][ty + i * 8]);
}

// ---------------------------------------------------------------------------
// 256x256 8-phase GEMM (T2+T3+T4+T5), BK=64, K=512 (8 K-tiles), 512 thr.
// MODE 0: NX=6; epilogue elu+1 -> q/k/v in NATIVE frag layout
//         [rb16][cb16][lane64][r4] (coalesced dwordx2 stores).
// MODE 1: NX=2; epilogue + bias -> fp32 row-major (64B-sector stores).
// ---------------------------------------------------------------------------
template <int MODE>
__global__ __launch_bounds__(512, 2) void gemm8_kernel(
    const u16* __restrict__ A, const u16* __restrict__ Bt,
    u16* __restrict__ qb, u16* __restrict__ kb, u16* __restrict__ vb,
    float* __restrict__ Cf, const float* __restrict__ bias) {
  constexpr int NX = (MODE == 0) ? 6 : 2;
  constexpr int K = 512;
  __shared__ __align__(16) u16 As[2][2][8192];  // 64 KB
  __shared__ __align__(16) u16 Bs[2][2][8192];  // 64 KB

  const int tid = threadIdx.x;
  const int lane = tid & 63;
  const int wid = tid >> 6;   // 0..7
  const int wr = wid >> 2;    // 0..1  (M)
  const int wcn = wid & 3;    // 0..3  (N)

  const int nwg = gridDim.x;
  const int pb = blockIdx.x;
  const int logical = (pb & 7) * (nwg >> 3) + (pb >> 3);
  const int rowBase = (logical / NX) * 256;
  const int colBase = (logical % NX) * 256;

  int soff[2], od[2];
#pragma unroll
  for (int i = 0; i < 2; ++i) {
    int o = (wid * 2 + i) * 1024 + lane * 16;        // linear dest byte
    int a = o ^ (((o >> 7) & 7) << 4);               // swizzled source coord
    soff[i] = (a >> 7) * K + ((a & 127) >> 1);       // element offset in panel
    od[i] = (wid * 2 + i) * 512;                     // dest base (elements)
  }
  const u16* Abase = A + (size_t)rowBase * K;
  const u16* Bbase = Bt + (size_t)colBase * K;

#define STAGE_A(tau, h)                                                      \
  { const u16* g = Abase + (size_t)(h)*128 * K + (tau)*64;                   \
    _Pragma("unroll") for (int i = 0; i < 2; ++i)                            \
        GLD_LDS16(g + soff[i], &As[(tau)&1][h][od[i]]); }
#define STAGE_B(tau, h)                                                      \
  { const u16* g = Bbase + (size_t)(h)*128 * K + (tau)*64;                   \
    _Pragma("unroll") for (int i = 0; i < 2; ++i)                            \
        GLD_LDS16(g + soff[i], &Bs[(tau)&1][h][od[i]]); }

  const int sx = (lane & 7) << 4;
  int rb[2];
#pragma unroll
  for (int ks = 0; ks < 2; ++ks)
    rb[ks] = ((lane & 15) * 128 + ks * 64 + (lane >> 4) * 16) ^ sx;
  const char* Ahalf[2] = {(const char*)&As[0][wr][0], (const char*)&As[1][wr][0]};
  const char* Bhalf[2] = {(const char*)&Bs[0][wcn >> 1][0], (const char*)&Bs[1][wcn >> 1][0]};

  bf16x8 aA[4][2], bB0[2][2], bB1[2][2];
  f32x4 acc[8][4];
  f32x4 zv = {0.f, 0.f, 0.f, 0.f};
#pragma unroll
  for (int m = 0; m < 8; ++m)
#pragma unroll
    for (int n = 0; n < 4; ++n) acc[m][n] = zv;

#define LDA_FRAGS(par, mh)                                                   \
  _Pragma("unroll") for (int m = 0; m < 4; ++m)                              \
      _Pragma("unroll") for (int ks = 0; ks < 2; ++ks)                       \
          aA[m][ks] = *(const bf16x8*)(Ahalf[par] + (mh)*8192 + m * 2048 + rb[ks]);
#define LDB_FRAGS(par, nh, dst)                                              \
  _Pragma("unroll") for (int n = 0; n < 2; ++n)                              \
      _Pragma("unroll") for (int ks = 0; ks < 2; ++ks)                       \
          dst[n][ks] = *(const bf16x8*)(Bhalf[par] + (wcn & 1) * 8192 +      \
                                        (nh)*4096 + n * 2048 + rb[ks]);
#define MFMA_QUAD(mh, nh, bsrc)                                              \
  __builtin_amdgcn_s_setprio(1);                                             \
  _Pragma("unroll") for (int m = 0; m < 4; ++m)                              \
      _Pragma("unroll") for (int n = 0; n < 2; ++n)                          \
          _Pragma("unroll") for (int ks = 0; ks < 2; ++ks)                   \
              acc[(mh)*4 + m][(nh)*2 + n] =                                  \
                  __builtin_amdgcn_mfma_f32_16x16x32_bf16(                   \
                      aA[m][ks], bsrc[n][ks], acc[(mh)*4 + m][(nh)*2 + n],   \
                      0, 0, 0);                                              \
  __builtin_amdgcn_s_setprio(0);

  // ---- prologue
  STAGE_A(0, 0); STAGE_A(0, 1); STAGE_B(0, 0); STAGE_B(0, 1);
  STAGE_B(1, 0); STAGE_A(1, 0);
  WAIT_VM(4);
  BAR();

  for (int t = 0; t < 6; t += 2) {
    LDA_FRAGS(0, 0); LDB_FRAGS(0, 0, bB0);
    STAGE_B(t + 1, 1);
    BAR(); WAIT_LGKM0();
    MFMA_QUAD(0, 0, bB0);
    BAR();
    LDB_FRAGS(0, 1, bB1);
    STAGE_A(t + 1, 1);
    BAR(); WAIT_LGKM0();
    MFMA_QUAD(0, 1, bB1);
    BAR();
    LDA_FRAGS(0, 1);
    STAGE_B(t + 2, 0);
    BAR(); WAIT_LGKM0();
    MFMA_QUAD(1, 1, bB1);
    BAR();
    STAGE_A(t + 2, 0);
    BAR(); WAIT_LGKM0();
    MFMA_QUAD(1, 0, bB0);
    WAIT_VM(4);
    BAR();
    LDA_FRAGS(1, 0); LDB_FRAGS(1, 0, bB0);
    STAGE_A(t + 2, 1);
    BAR(); WAIT_LGKM0();
    MFMA_QUAD(0, 0, bB0);
    BAR();
    LDB_FRAGS(1, 1, bB1);
    STAGE_B(t + 2, 1);
    BAR(); WAIT_LGKM0();
    MFMA_QUAD(0, 1, bB1);
    BAR();
    LDA_FRAGS(1, 1);
    STAGE_B(t + 3, 0);
    BAR(); WAIT_LGKM0();
    MFMA_QUAD(1, 1, bB1);
    BAR();
    STAGE_A(t + 3, 0);
    BAR(); WAIT_LGKM0();
    MFMA_QUAD(1, 0, bB0);
    WAIT_VM(4);
    BAR();
  }

  // ---- drain pair (6,7)
  LDA_FRAGS(0, 0); LDB_FRAGS(0, 0, bB0);
  STAGE_B(7, 1);
  BAR(); WAIT_LGKM0();
  MFMA_QUAD(0, 0, bB0);
  BAR();
  LDB_FRAGS(0, 1, bB1);
  STAGE_A(7, 1);
  BAR(); WAIT_LGKM0();
  MFMA_QUAD(0, 1, bB1);
  BAR();
  LDA_FRAGS(0, 1);
  BAR(); WAIT_LGKM0();
  MFMA_QUAD(1, 1, bB1);
  BAR();
  BAR(); WAIT_LGKM0();
  MFMA_QUAD(1, 0, bB0);
  WAIT_VM(0);
  BAR();
  LDA_FRAGS(1, 0); LDB_FRAGS(1, 0, bB0);
  BAR(); WAIT_LGKM0();
  MFMA_QUAD(0, 0, bB0);
  BAR();
  LDB_FRAGS(1, 1, bB1);
  BAR(); WAIT_LGKM0();
  MFMA_QUAD(0, 1, bB1);
  BAR();
  LDA_FRAGS(1, 1);
  BAR(); WAIT_LGKM0();
  MFMA_QUAD(1, 1, bB1);
  BAR();
  BAR(); WAIT_LGKM0();
  MFMA_QUAD(1, 0, bB0);

  // ---- epilogue
  if (MODE == 0) {
    // NATIVE layout: [rb][cb][lane][r4]; coalesced 8B stores
    u16* dst = (colBase < 512) ? qb : (colBase < 1024) ? kb : vb;
    const int cb2 = colBase & 511;
    const bool doelu = (colBase < 1024);
    const int rbBase = (rowBase >> 4) + wr * 8;
    const int cbBase = (cb2 >> 4) + wcn * 4;
#pragma unroll
    for (int mi = 0; mi < 8; ++mi) {
#pragma unroll
      for (int ni = 0; ni < 4; ++ni) {
        float v[4];
#pragma unroll
        for (int r = 0; r < 4; ++r) {
          float t2 = acc[mi][ni][r];
          v[r] = doelu ? ((t2 > 0.f) ? t2 + 1.f : __expf(t2)) : t2;
        }
        unsigned lo = (unsigned)f2bf(v[0]) | ((unsigned)f2bf(v[1]) << 16);
        unsigned hi = (unsigned)f2bf(v[2]) | ((unsigned)f2bf(v[3]) << 16);
        size_t base = (((size_t)(rbBase + mi) * 32 + (cbBase + ni)) * 64 + lane) * 4;
        *(uint2*)(dst + base) = make_uint2(lo, hi);
      }
    }
  } else {
#pragma unroll
    for (int mi = 0; mi < 8; ++mi) {
#pragma unroll
      for (int ni = 0; ni < 4; ++ni) {
        const int col = colBase + wcn * 64 + ni * 16 + (lane & 15);
#pragma unroll
        for (int r = 0; r < 4; ++r) {
          const int row = rowBase + wr * 128 + mi * 16 + (lane >> 4) * 4 + r;
          Cf[(size_t)row * 512 + col] = acc[mi][ni][r] + bias[col];
        }
      }
    }
  }
#undef STAGE_A
#undef STAGE_B
#undef LDA_FRAGS
#undef LDB_FRAGS
#undef MFMA_QUAD
}

// ---------------------------------------------------------------------------
// kv partials via MFMA. Block = (chunk of 1024 rows, bh); 4 waves K-split
// 256 rows each. k,v read in NATIVE frag layout, transposed into per-wave
// XOR-swizzled LDS kT/vT[64 d][64 n]; a-frag = kT, b-frag = vT; ksum via
// ones b-frag. Cross-wave reduce in LDS -> part[bh][chunk][64][80].
// ---------------------------------------------------------------------------
__global__ __launch_bounds__(256, 2) void kv_partial_mfma(
    const u16* __restrict__ kb, const u16* __restrict__ vb,
    float* __restrict__ part) {
  __shared__ __align__(16) char lds[81920];  // 4x16KB staging / 80KB reduce
  const int tid = threadIdx.x, lane = tid & 63, wid = tid >> 6;
  const int chunk = blockIdx.x;  // 0..7 (1024 rows)
  const int bh = blockIdx.y;     // 0..31
  const int b = bh >> 3, h = bh & 7;
  const int hcb = h * 4;

  char* kTc = lds + wid * 16384;       // [64 d][64 n] u16, swizzled
  char* vTc = kTc + 8192;
  const int rb0 = b * 512 + chunk * 64 + wid * 16;  // 16-row block index

  uint4 kreg[8], vreg[8];

#define KV_LOAD(it)                                                          \
  _Pragma("unroll") for (int q = 0; q < 8; ++q) {                            \
    int u = q * 64 + lane;                                                   \
    int fid = u >> 5, w = u & 31;                                            \
    int rbl = fid >> 2, cbi = fid & 3;                                       \
    size_t fb = ((size_t)(rb0 + (it)*4 + rbl) * 32 + hcb + cbi) * 32 + w;    \
    kreg[q] = ((const uint4*)kb)[fb];                                        \
    vreg[q] = ((const uint4*)vb)[fb];                                        \
  }

#define KV_WRITE()                                                           \
  _Pragma("unroll") for (int q = 0; q < 8; ++q) {                            \
    int u = q * 64 + lane;                                                   \
    int fid = u >> 5, w = u & 31;                                            \
    int rbl = fid >> 2, cbi = fid & 3;                                       \
    int l0 = 2 * w;                                                          \
    int d0 = cbi * 16 + (l0 & 15);                                           \
    int n0 = rbl * 16 + (l0 >> 4) * 4;                                       \
    int a0 = swz(d0 * 128 + n0 * 2);                                         \
    int a1 = swz((d0 + 1) * 128 + n0 * 2);                                   \
    *(uint2*)(kTc + a0) = make_uint2(kreg[q].x, kreg[q].y);                  \
    *(uint2*)(kTc + a1) = make_uint2(kreg[q].z, kreg[q].w);                  \
    *(uint2*)(vTc + a0) = make_uint2(vreg[q].x, vreg[q].y);                  \
    *(uint2*)(vTc + a1) = make_uint2(vreg[q].z, vreg[q].w);                  \
  }

  const uint4 onesu = make_uint4(0x3F803F80u, 0x3F803F80u, 0x3F803F80u, 0x3F803F80u);
  const bf16x8 ones = __builtin_bit_cast(bf16x8, onesu);

  f32x4 zv = {0.f, 0.f, 0.f, 0.f};
  f32x4 acc[4][5];
#pragma unroll
  for (int mb = 0; mb < 4; ++mb)
#pragma unroll
    for (int eb = 0; eb < 5; ++eb) acc[mb][eb] = zv;

  KV_LOAD(0);
#pragma unroll
  for (int it = 0; it < 4; ++it) {
    WAIT_VM(0);                 // kreg/vreg for iter `it` resident
    KV_WRITE();                 // ds_writes consume regs at issue
    if (it < 3) KV_LOAD(it + 1);  // issue next loads (hide under MFMA)
    WAIT_LGKM0();               // transpose-writes visible
#pragma unroll
    for (int ks = 0; ks < 2; ++ks) {
      bf16x8 afr[4], bvf[4];
#pragma unroll
      for (int mb = 0; mb < 4; ++mb)
        afr[mb] = *(const bf16x8*)(kTc + swz((mb * 16 + (lane & 15)) * 128 +
                                             (ks * 32 + (lane >> 4) * 8) * 2));
#pragma unroll
      for (int eb = 0; eb < 4; ++eb)
        bvf[eb] = *(const bf16x8*)(vTc + swz((eb * 16 + (lane & 15)) * 128 +
                                             (ks * 32 + (lane >> 4) * 8) * 2));
      WAIT_LGKM0();
#pragma unroll
      for (int mb = 0; mb < 4; ++mb) {
#pragma unroll
        for (int eb = 0; eb < 4; ++eb)
          acc[mb][eb] = __builtin_amdgcn_mfma_f32_16x16x32_bf16(
              afr[mb], bvf[eb], acc[mb][eb], 0, 0, 0);
        acc[mb][4] = __builtin_amdgcn_mfma_f32_16x16x32_bf16(
            afr[mb], ones, acc[mb][4], 0, 0, 0);
      }
    }
  }

  // ---- cross-wave reduce through LDS
  __syncthreads();   // all waves done with their staging regions
  float* red = (float*)lds;  // [wid][20 frags][64 lanes][4]
#pragma unroll
  for (int mb = 0; mb < 4; ++mb)
#pragma unroll
    for (int eb = 0; eb < 5; ++eb)
      ((f32x4*)red)[wid * 1280 + (mb * 5 + eb) * 64 + lane] = acc[mb][eb];
  __syncthreads();

  float* pp = part + ((size_t)bh * 8 + chunk) * 5120;
  const int lane_s = tid >> 2, r = tid & 3;
#pragma unroll
  for (int fi = 0; fi < 20; ++fi) {
    float s = red[fi * 256 + tid] + red[5120 + fi * 256 + tid] +
              red[10240 + fi * 256 + tid] + red[15360 + fi * 256 + tid];
    const int mb = fi / 5, eb = fi % 5;
    const int d = mb * 16 + (lane_s >> 4) * 4 + r;
    if (eb < 4) {
      pp[d * 80 + eb * 16 + (lane_s & 15)] = s;
    } else if ((lane_s & 15) == 0) {
      pp[d * 80 + 64] = s;
    }
  }
#undef KV_LOAD
#undef KV_WRITE
}

// ---------------------------------------------------------------------------
// Reduce partials over 8 chunks -> kv_ext[bh][64][80]; cols 65..79 zeroed.
// ---------------------------------------------------------------------------
__global__ void kv_reduce_kernel(const float* __restrict__ part,
                                 float* __restrict__ kv_ext) {
  const int idx = blockIdx.x * 256 + threadIdx.x;
  const int bh = idx / 5120;
  const int de = idx % 5120;
  const int e = de % 80;
  float s = 0.f;
  if (e <= 64) {
    for (int c = 0; c < 8; ++c) s += part[((size_t)bh * 8 + c) * 5120 + de];
  }
  kv_ext[idx] = s;
}

// ---------------------------------------------------------------------------
// attn = (q @ kv) * z, q read NATIVE, output written ROW-MAJOR via per-wave
// LDS transpose (XOR-swizzled qs).
// ---------------------------------------------------------------------------
__global__ __launch_bounds__(256, 2) void attn_kernel(
    const u16* __restrict__ qb, const float* __restrict__ kv_ext,
    u16* __restrict__ attn) {
  __shared__ __align__(16) float kvs[64 * 80];
  __shared__ __align__(16) u16 qs[4][64 * 64];
  const int tid = threadIdx.x, lane = tid & 63, wid = tid >> 6;
  const int nchunk = blockIdx.x, bh = blockIdx.y;
  const int b = bh >> 3, h = bh & 7;

#pragma unroll
  for (int i = 0; i < 20; ++i)
    kvs[i * 256 + tid] = kv_ext[(size_t)bh * 5120 + i * 256 + tid];
  __syncthreads();

  bf16x8 bfr[5][2];
#pragma unroll
  for (int eb = 0; eb < 5; ++eb)
#pragma unroll
    for (int ksi = 0; ksi < 2; ++ksi) {
      unsigned pw[4];
#pragma unroll
      for (int jj = 0; jj < 4; ++jj) {
        int d0 = ksi * 32 + (lane >> 4) * 8 + 2 * jj;
        int e = eb * 16 + (lane & 15);
        unsigned lo = f2bf(kvs[d0 * 80 + e]);
        unsigned hi = f2bf(kvs[(d0 + 1) * 80 + e]);
        pw[jj] = lo | (hi << 16);
      }
      uint4 u = make_uint4(pw[0], pw[1], pw[2], pw[3]);
      bfr[eb][ksi] = __builtin_bit_cast(bf16x8, u);
    }

  // stage this wave's 64 q rows from NATIVE layout into row-major swizzled qs
  const size_t row0 = (size_t)b * 8192 + (size_t)nchunk * 256 + wid * 64;
  const int rbQ = (int)(row0 >> 4);
  const int hcbQ = h * 4;
  char* qsw = (char*)&qs[wid][0];
#pragma unroll
  for (int it = 0; it < 8; ++it) {
    int flat = it * 64 + lane;            // 0..511
    int frag = flat >> 5, w = flat & 31;
    int rb_i = frag >> 2, cb_i = frag & 3;
    size_t src = (((size_t)(rbQ + rb_i) * 32 + hcbQ + cb_i) * 64 + w * 2) * 4;
    uint4 q4 = *(const uint4*)(qb + src);
    int l0 = w * 2;
    int row = rb_i * 16 + ((l0 >> 4) << 2);
    int col = cb_i * 16 + (l0 & 15);
    int bb = row * 128 + col * 2;
    *(unsigned*)(qsw + swz(bb)) = (q4.x & 0xFFFF) | ((q4.z & 0xFFFF) << 16);
    *(unsigned*)(qsw + swz(bb + 128)) = (q4.x >> 16) | (q4.z & 0xFFFF0000u);
    *(unsigned*)(qsw + swz(bb + 256)) = (q4.y & 0xFFFF) | ((q4.w & 0xFFFF) << 16);
    *(unsigned*)(qsw + swz(bb + 384)) = (q4.y >> 16) | (q4.w & 0xFFFF0000u);
  }
  WAIT_LGKM0();

  f32x4 zv = {0.f, 0.f, 0.f, 0.f};
  f32x4 acc[4][5];
#pragma unroll
  for (int m = 0; m < 4; ++m)
#pragma unroll
    for (int eb = 0; eb < 5; ++eb) acc[m][eb] = zv;

#pragma unroll
  for (int m = 0; m < 4; ++m)
#pragma unroll
    for (int ksi = 0; ksi < 2; ++ksi) {
      int bb = (m * 16 + (lane & 15)) * 128 + (ksi * 32 + (lane >> 4) * 8) * 2;
      bf16x8 af = *(const bf16x8*)(qsw + swz(bb));
#pragma unroll
      for (int eb = 0; eb < 5; ++eb)
        acc[m][eb] = __builtin_amdgcn_mfma_f32_16x16x32_bf16(af, bfr[eb][ksi], acc[m][eb], 0, 0, 0);
    }

  // scale + per-wave LDS transpose (qs[wid] dead now) -> coalesced stores
#pragma unroll
  for (int m = 0; m < 4; ++m) {
#pragma unroll
    for (int r = 0; r < 4; ++r) {
      float den = __shfl(acc[m][4][r], lane & ~15, 64);
      float zr = 1.f / (den + 1e-6f);
      int row = m * 16 + (lane >> 4) * 4 + r;
#pragma unroll
      for (int eb = 0; eb < 4; ++eb) {
        int col = eb * 16 + (lane & 15);
        *(u16*)(qsw + swz(row * 128 + col * 2)) = f2bf(acc[m][eb][r] * zr);
      }
    }
  }
  WAIT_LGKM0();
#pragma unroll
  for (int jt = 0; jt < 8; ++jt) {
    int flat = jt * 64 + lane;            // 64 rows x 8 x 16B
    int row = flat >> 3, w = flat & 7;
    uint4 val = *(const uint4*)(qsw + swz(row * 128 + w * 16));
    *(uint4*)(attn + (row0 + row) * 512 + h * 64 + w * 8) = val;
  }
}

// ---------------------------------------------------------------------------
extern "C" void kernel_launch(void* const* d_in, const int* in_sizes, int n_in,
                              void* d_out, int out_size, void* d_ws, size_t ws_size,
                              hipStream_t stream) {
  const float* x = (const float*)d_in[0];
  const float* Wqkv = (const float*)d_in[1];
  const float* Wout = (const float*)d_in[2];
  const float* bout = (const float*)d_in[3];
  float* out = (float*)d_out;

  char* ws = (char*)d_ws;
  u16* qb = (u16*)ws;        ws += (size_t)32768 * 512 * 2;  // native
  u16* kb = (u16*)ws;        ws += (size_t)32768 * 512 * 2;  // native
  u16* vb = (u16*)ws;        ws += (size_t)32768 * 512 * 2;  // native; reused row-major as attn
  u16* wqkv_t = (u16*)ws;    ws += (size_t)1536 * 512 * 2;
  u16* wout_t = (u16*)ws;    ws += (size_t)512 * 512 * 2;
  float* kv_ext = (float*)ws; ws += (size_t)32 * 64 * 80 * 4;
  float* part = (float*)ws;   ws += (size_t)32 * 8 * 64 * 80 * 4;

  u16* xb = (u16*)d_out;  // dead until gemm1 overwrites d_out

  convert_bf16_kernel<<<8192, 256, 0, stream>>>(x, xb);
  transpose_bf16<<<dim3(1536 / 32, 512 / 32), 256, 0, stream>>>(Wqkv, wqkv_t, 512, 1536);
  transpose_bf16<<<dim3(512 / 32, 512 / 32), 256, 0, stream>>>(Wout, wout_t, 512, 512);
  gemm8_kernel<0><<<768, 512, 0, stream>>>(xb, wqkv_t, qb, kb, vb, nullptr, nullptr);
  kv_partial_mfma<<<dim3(8, 32), 256, 0, stream>>>(kb, vb, part);
  kv_reduce_kernel<<<640, 256, 0, stream>>>(part, kv_ext);
  attn_kernel<<<dim3(32, 32), 256, 0, stream>>>(qb, kv_ext, vb);
  gemm8_kernel<1><<<256, 512, 0, stream>>>(vb, wout_t, nullptr, nullptr, nullptr, out, bout);
}